// Round 16
// baseline (2434.562 us; speedup 1.0000x reference)
//
#include <hip/hip_runtime.h>
#include <stdint.h>

#define NP 1024
#define NV 49408
#define ND 512
// B packed: [row][hi(512)|lo(512)] bf16 (2048 B/row).
// A packed FRAGMENT-ORDERED: chunk(t, mb, lane) at byte ((t*64+mb)*64+lane)*16
//   t = phys 32-k tile (0..31: 16 hi, 16 lo), mb = row>>4, lane = g*16+r holds
//   A[mb*16+r][t*32 + g*8 .. +7]. A wave's frag load = 1 KB contiguous.
// Logical K=1536, 3-term split, 32-k steps -> 48 tiles:
//   A phys tile = t & 31                  (ah x16, al x16, ah x16)
//   B phys byte = (t & 15) * 64 + (t >= 32 ? 1024 : 0)   (bh, bh, bl)
#define NTILE 48

typedef __attribute__((ext_vector_type(8))) __bf16 bf16x8;
typedef __attribute__((ext_vector_type(4))) float f32x4;
typedef __attribute__((ext_vector_type(4))) int i32x4;

__device__ inline unsigned long long pack_sv(float s, unsigned v) {
  unsigned u = __float_as_uint(s);
  u = (u & 0x80000000u) ? ~u : (u | 0x80000000u);  // orderable map
  return ((unsigned long long)u << 32) | (unsigned long long)v;
}

// A-pack: bf16 hi/lo split, FRAGMENT-ORDERED layout (see header comment).
__global__ __launch_bounds__(256) void pack_a_k(const float* __restrict__ src,
                                                __bf16* __restrict__ dst) {
  int lane = threadIdx.x & 63;
  int row = blockIdx.x * 4 + (threadIdx.x >> 6);
  const float* r = src + (size_t)row * ND + lane * 8;
  float4 x0 = *(const float4*)r;
  float4 x1 = *(const float4*)(r + 4);
  float xs[8] = {x0.x, x0.y, x0.z, x0.w, x1.x, x1.y, x1.z, x1.w};
  bf16x8 hi, lo;
#pragma unroll
  for (int j = 0; j < 8; ++j) {
    float x = xs[j];
    __bf16 h = (__bf16)x;
    hi[j] = h;
    lo[j] = (__bf16)(x - (float)h);   // exact residual, then RTNE to bf16
  }
  const int mb = row >> 4, rr = row & 15;
  const int tHi = lane >> 2, g = lane & 3;
  size_t cHi = (((size_t)tHi * 64) + mb) * 64 + g * 16 + rr;        // chunk idx
  size_t cLo = (((size_t)(tHi + 16) * 64) + mb) * 64 + g * 16 + rr;
  *(bf16x8*)(dst + cHi * 8) = hi;
  *(bf16x8*)(dst + cLo * 8) = lo;
}

// B-pack: [row][hi|lo] + exact f32 sum of squares per row.
__global__ __launch_bounds__(256) void pack_b_k(const float* __restrict__ src,
                                                __bf16* __restrict__ dst,
                                                float* __restrict__ sumsq) {
  int lane = threadIdx.x & 63;
  int row = blockIdx.x * 4 + (threadIdx.x >> 6);
  const float* r = src + (size_t)row * ND + lane * 8;
  float4 x0 = *(const float4*)r;
  float4 x1 = *(const float4*)(r + 4);
  float xs[8] = {x0.x, x0.y, x0.z, x0.w, x1.x, x1.y, x1.z, x1.w};
  bf16x8 hi, lo;
  float ss = 0.f;
#pragma unroll
  for (int j = 0; j < 8; ++j) {
    float x = xs[j];
    ss += x * x;
    __bf16 h = (__bf16)x;
    hi[j] = h;
    lo[j] = (__bf16)(x - (float)h);
  }
  __bf16* drow = dst + (size_t)row * 1024 + lane * 8;
  *(bf16x8*)drow = hi;
  *(bf16x8*)(drow + 512) = lo;
#pragma unroll
  for (int m = 1; m < 64; m <<= 1) ss += __shfl_xor(ss, m);
  if (lane == 0) sumsq[row] = ss;
}

// ---- 128x256 tile, BK=32, 8 waves (2Mx4N), 3 blocks/CU ---------------------
// R15 lesson: bytes/FLOP and occupancy are COUPLED - the ~60 B/cyc/CU
// sustained data-path rate needs 3 resident blocks. This tile improves
// bytes/KFLOP (45.8 -> 38) while KEEPING per-thread registers (~150) and
// 3 blocks/CU (LDS 48 KB x 3 = 144 <= 160), and doubles waves/CU to 24.
// Schedule = R13's (proven absmax=0), per phase p:
//   [4x A-pref(p+1), 1KB-contiguous] [2x gll16 B(p+2) -> region (p+2)%3]
//   [4x asm ds_read B(p) from region p%3] [s_waitcnt vmcnt(6) lgkmcnt(0)]
//   [sched_barrier] [16 MFMA] [s_barrier].
// vmcnt(6) leaves this phase's 6 VMEM (4 A + 2 stage) -> drains p-1's A(p)
// (consumed now) and Bst(p+1) (published by this barrier, read at p+1).
// lgkm0 BEFORE the barrier is load-bearing (R12 lesson: WAR on regions).
// B region = 256 rows x 64 B = 16 KB = 4 groups of 64 rows; slot swizzle
// per group (R6-verified, 0 conflicts): q(row,c16) = (row>>1)*8 + (row&1)*4
// + ((c16+(row>>1))&3). Stage-side tid->(srow,sc16) map extends to 512
// threads consistently (group boundary at tid 256; 32&3==0).

__device__ __attribute__((always_inline)) static inline
void gll16(const char* src, char* dst) {
  __builtin_amdgcn_global_load_lds(
      (const __attribute__((address_space(1))) void*)src,
      (__attribute__((address_space(3))) void*)dst, 16, 0, 0);
}

__device__ __attribute__((always_inline)) static inline
bf16x8 lds_read(unsigned addr) {
  i32x4 d;
  asm volatile("ds_read_b128 %0, %1" : "=v"(d) : "v"(addr));
  return __builtin_bit_cast(bf16x8, d);
}

#define FENCE asm volatile("" ::: "memory")

__device__ __attribute__((always_inline)) static inline
int bByte(int t) {                    // B phys byte for logical tile t (wraps)
  int tt = (t < NTILE) ? t : t - NTILE;
  return (tt & 15) * 64 + (tt >= 32 ? 1024 : 0);
}

template <int J>
__device__ __attribute__((always_inline)) static inline
void phase_op(f32x4 (&acc)[4][4], bf16x8 (&aE)[4], bf16x8 (&aO)[4],
              const char* Ab, const int (&voffA)[4],
              const char* srcBt, char* stB, unsigned bRead, int p) {
  constexpr int R = J % 3;
  constexpr int RS = (J + 2) % 3;
  const int kA = ((p + 1) & 31) * 65536;   // A tile p+1 (48&31=16: dead, in-bounds)
  const int kB = bByte(p + 2);             // B tile p+2
  bf16x8 (&aN)[4] = (J % 2 == 0) ? aO : aE;   // prefetch target
  bf16x8 (&aC)[4] = (J % 2 == 0) ? aE : aO;   // compute source
  // A prefetch for next phase (plain loads, 1KB contiguous per frag)
#pragma unroll
  for (int m = 0; m < 4; ++m)
    aN[m] = *(const bf16x8*)(Ab + voffA[m] + kA);
  // B stage for phase p+2 (region RS died at phase p-1); 512 thr x 16 B x 2
  gll16(srcBt + kB, stB + RS * 16384);
  gll16(srcBt + kB + 262144, stB + RS * 16384 + 8192);
  // B fragment reads for this phase
  bf16x8 b[4];
#pragma unroll
  for (int n = 0; n < 4; ++n)
    b[n] = lds_read(bRead + R * 16384 + n * 1024);
  asm volatile("s_waitcnt vmcnt(6) lgkmcnt(0)" ::: "memory");
  __builtin_amdgcn_sched_barrier(0);
  __builtin_amdgcn_s_setprio(1);
#pragma unroll
  for (int m = 0; m < 4; ++m)
#pragma unroll
    for (int n = 0; n < 4; ++n)
      acc[m][n] = __builtin_amdgcn_mfma_f32_16x16x32_bf16(aC[m], b[n], acc[m][n], 0, 0, 0);
  __builtin_amdgcn_s_setprio(0);
  FENCE;
  __builtin_amdgcn_s_barrier();
  FENCE;
}

__global__ __launch_bounds__(512, 6) void gemm_argmin_k(const __bf16* __restrict__ A,
                                                        const __bf16* __restrict__ B,
                                                        const float* __restrict__ b2,
                                                        unsigned long long* __restrict__ best) {
  __shared__ __align__(16) char lds[49152];
  const int tid = threadIdx.x;
  const int lane = tid & 63;
  const int wid = tid >> 6;   // 0..7
  const int wm = wid >> 2;    // 2 wave-rows (64 rows each)
  const int wn = wid & 3;     // 4 wave-cols (64 cols each)

  // XCD-chunk swizzle (1544 = 8*193 -> bijective): 8 consecutive o share a
  // B-panel on one XCD -> panel L2-resident (R6: FETCH 606->64 MB).
  const int d = blockIdx.x;
  const int o = (d & 7) * 193 + (d >> 3);
  const int bm = (o & 7) * 128;
  const int bn = (o >> 3) * 256;

  const int r = lane & 15, g = lane >> 4;
  const int rh = r >> 1;
  const unsigned lds0 =
      (unsigned)(uintptr_t)(const __attribute__((address_space(3))) char*)(const char*)lds;
  const unsigned bRead = lds0 + wn * 4096 + rh * 128 + (r & 1) * 64 + (((g + rh) & 3) << 4);

  // A per-lane byte offsets, fragment-ordered layout:
  const char* Ab = (const char*)A;
  int voffA[4];
#pragma unroll
  for (int m = 0; m < 4; ++m)
    voffA[m] = ((bm >> 4) + wm * 4 + m) * 1024 + lane * 16;

  // B stage-side lane mapping (inverse of the slot swizzle); 512 threads
  // cover 1024 slots (rows 0-127; rows 128-255 via 2nd gll16 at +262144)
  const int srow = 2 * (tid >> 3) + ((tid >> 2) & 1);
  const int sc16 = ((tid & 3) - (tid >> 3)) & 3;
  const char* srcBt = (const char*)B + (size_t)(bn + srow) * 2048 + sc16 * 16;
  char* stB = (char*)lds + tid * 16;

  f32x4 acc[4][4] = {};
  bf16x8 aE[4], aO[4];

  // prologue: A(0) -> aE, Bstage(0)->R0, Bstage(1)->R1; drain to 2
#pragma unroll
  for (int m = 0; m < 4; ++m)
    aE[m] = *(const bf16x8*)(Ab + voffA[m]);
  gll16(srcBt + bByte(0), stB + 0);
  gll16(srcBt + bByte(0) + 262144, stB + 8192);
  gll16(srcBt + bByte(1), stB + 16384);
  gll16(srcBt + bByte(1) + 262144, stB + 16384 + 8192);
  asm volatile("s_waitcnt vmcnt(2)" ::: "memory");
  FENCE;
  __builtin_amdgcn_s_barrier();
  FENCE;

#pragma unroll 1
  for (int it = 0; it < 8; ++it) {
    const int p0 = 6 * it;
    phase_op<0>(acc, aE, aO, Ab, voffA, srcBt, stB, bRead, p0 + 0);
    phase_op<1>(acc, aE, aO, Ab, voffA, srcBt, stB, bRead, p0 + 1);
    phase_op<2>(acc, aE, aO, Ab, voffA, srcBt, stB, bRead, p0 + 2);
    phase_op<3>(acc, aE, aO, Ab, voffA, srcBt, stB, bRead, p0 + 3);
    phase_op<4>(acc, aE, aO, Ab, voffA, srcBt, stB, bRead, p0 + 4);
    phase_op<5>(acc, aE, aO, Ab, voffA, srcBt, stB, bRead, p0 + 5);
  }

  // epilogue: fused argmin. C/D map: col = lane&15, row = (lane>>4)*4 + reg.
  float bb[4];
#pragma unroll
  for (int n = 0; n < 4; ++n) bb[n] = b2[bn + wn * 64 + n * 16 + r];
#pragma unroll
  for (int m = 0; m < 4; ++m) {
#pragma unroll
    for (int reg = 0; reg < 4; ++reg) {
      unsigned long long pk = ~0ull;
#pragma unroll
      for (int n = 0; n < 4; ++n) {
        float s = bb[n] - 2.0f * acc[m][n][reg];
        unsigned long long cand = pack_sv(s, (unsigned)(bn + wn * 64 + n * 16 + r));
        pk = (cand < pk) ? cand : pk;
      }
#pragma unroll
      for (int msk = 1; msk < 16; msk <<= 1) {
        unsigned long long o2 = __shfl_xor(pk, msk);
        pk = (o2 < pk) ? o2 : pk;
      }
      if (r == 0) atomicMin(&best[bm + wm * 64 + m * 16 + g * 4 + reg], pk);
    }
  }
}

// Fallback (small ws): exact fp32 squared distance, fused argmin.
__global__ __launch_bounds__(256) void naive_argmin_k(const float* __restrict__ A,
                                                      const float* __restrict__ B,
                                                      unsigned long long* __restrict__ best) {
  __shared__ float arow[ND];
  int p = blockIdx.y;
  unsigned v = blockIdx.x * 256 + threadIdx.x;
  for (int i = threadIdx.x; i < ND; i += 256) arow[i] = A[(size_t)p * ND + i];
  __syncthreads();
  const float4* br = (const float4*)(B + (size_t)v * ND);
  float s = 0.f;
#pragma unroll 4
  for (int i = 0; i < ND / 4; ++i) {
    float4 b = br[i];
    const float4 a = *(const float4*)&arow[i * 4];
    float d0 = a.x - b.x, d1 = a.y - b.y, d2 = a.z - b.z, d3 = a.w - b.w;
    s += d0 * d0 + d1 * d1 + d2 * d2 + d3 * d3;
  }
  unsigned long long pk = pack_sv(s, v);
#pragma unroll
  for (int msk = 1; msk < 64; msk <<= 1) {
    unsigned long long o = __shfl_xor(pk, msk);
    pk = (o < pk) ? o : pk;
  }
  if ((threadIdx.x & 63) == 0) atomicMin(&best[p], pk);
}

// Gather winning rows + ids (ids written as float, d_out is read as flat f32).
__global__ __launch_bounds__(128) void gather_k(const unsigned long long* __restrict__ best,
                                                const float* __restrict__ clip,
                                                float* __restrict__ out) {
  int p = blockIdx.x;
  unsigned long long pk = best[p];
  unsigned v = (unsigned)(pk & 0xffffffffull);
  const float4* src = (const float4*)(clip + (size_t)v * ND);
  float4* dst = (float4*)(out + (size_t)p * ND);
  dst[threadIdx.x] = src[threadIdx.x];
  if (threadIdx.x == 0) out[(size_t)NP * ND + p] = (float)v;
}

extern "C" void kernel_launch(void* const* d_in, const int* in_sizes, int n_in,
                              void* d_out, int out_size, void* d_ws, size_t ws_size,
                              hipStream_t stream) {
  const float* prompt = (const float*)d_in[0];
  const float* clip = (const float*)d_in[1];
  float* out = (float*)d_out;

  // workspace layout
  size_t off = 0;
  unsigned long long* best = (unsigned long long*)d_ws;
  off += (size_t)NP * 8;
  float* b2 = (float*)((char*)d_ws + off);
  off += (size_t)NV * 4;
  off = (off + 255) & ~(size_t)255;
  __bf16* Ap = (__bf16*)((char*)d_ws + off);
  off += (size_t)NP * 1024 * 2;                // 2 MiB  fragment-ordered
  __bf16* Bp = (__bf16*)((char*)d_ws + off);
  off += (size_t)NV * 1024 * 2;                // 96.5 MiB [hi|lo]
  const size_t need = off;

  if (ws_size >= need) {
    hipMemsetAsync(best, 0xFF, (size_t)NP * 8, stream);
    pack_a_k<<<NP / 4, 256, 0, stream>>>(prompt, Ap);
    pack_b_k<<<NV / 4, 256, 0, stream>>>(clip, Bp, b2);
    gemm_argmin_k<<<dim3((NP / 128) * (NV / 256)), 512, 0, stream>>>(Ap, Bp, b2, best);
    gather_k<<<NP, 128, 0, stream>>>(best, clip, out);
  } else {
    // fallback: exact fp32, needs only the 8 KiB `best` array
    hipMemsetAsync(best, 0xFF, (size_t)NP * 8, stream);
    dim3 grid(NV / 256, NP);
    naive_argmin_k<<<grid, 256, 0, stream>>>(prompt, clip, best);
    gather_k<<<NP, 128, 0, stream>>>(best, clip, out);
  }
}

// Round 17
// 213.061 us; speedup vs baseline: 11.4266x; 11.4266x over previous
//
#include <hip/hip_runtime.h>
#include <stdint.h>

#define NP 1024
#define NV 49408
#define ND 512
// B packed: [row][hi(512)|lo(512)] bf16 (2048 B/row).
// A packed FRAGMENT-ORDERED: chunk(t, mb, lane) at byte ((t*64+mb)*64+lane)*16
//   t = phys 32-k tile (0..31: 16 hi, 16 lo), mb = row>>4, lane = g*16+r holds
//   A[mb*16+r][t*32 + g*8 .. +7]. A wave's frag load = 1 KB contiguous.
// Logical K=1536, 3-term split, 32-k steps -> 48 tiles:
//   A phys tile = t & 31                  (ah x16, al x16, ah x16)
//   B phys byte = (t & 15) * 64 + (t >= 32 ? 1024 : 0)   (bh, bh, bl)
#define NTILE 48

typedef __attribute__((ext_vector_type(8))) __bf16 bf16x8;
typedef __attribute__((ext_vector_type(4))) float f32x4;
typedef __attribute__((ext_vector_type(4))) int i32x4;

__device__ inline unsigned long long pack_sv(float s, unsigned v) {
  unsigned u = __float_as_uint(s);
  u = (u & 0x80000000u) ? ~u : (u | 0x80000000u);  // orderable map
  return ((unsigned long long)u << 32) | (unsigned long long)v;
}

// A-pack: bf16 hi/lo split, FRAGMENT-ORDERED layout (see header comment).
__global__ __launch_bounds__(256) void pack_a_k(const float* __restrict__ src,
                                                __bf16* __restrict__ dst) {
  int lane = threadIdx.x & 63;
  int row = blockIdx.x * 4 + (threadIdx.x >> 6);
  const float* r = src + (size_t)row * ND + lane * 8;
  float4 x0 = *(const float4*)r;
  float4 x1 = *(const float4*)(r + 4);
  float xs[8] = {x0.x, x0.y, x0.z, x0.w, x1.x, x1.y, x1.z, x1.w};
  bf16x8 hi, lo;
#pragma unroll
  for (int j = 0; j < 8; ++j) {
    float x = xs[j];
    __bf16 h = (__bf16)x;
    hi[j] = h;
    lo[j] = (__bf16)(x - (float)h);   // exact residual, then RTNE to bf16
  }
  const int mb = row >> 4, rr = row & 15;
  const int tHi = lane >> 2, g = lane & 3;
  size_t cHi = (((size_t)tHi * 64) + mb) * 64 + g * 16 + rr;        // chunk idx
  size_t cLo = (((size_t)(tHi + 16) * 64) + mb) * 64 + g * 16 + rr;
  *(bf16x8*)(dst + cHi * 8) = hi;
  *(bf16x8*)(dst + cLo * 8) = lo;
}

// B-pack: [row][hi|lo] + exact f32 sum of squares per row.
__global__ __launch_bounds__(256) void pack_b_k(const float* __restrict__ src,
                                                __bf16* __restrict__ dst,
                                                float* __restrict__ sumsq) {
  int lane = threadIdx.x & 63;
  int row = blockIdx.x * 4 + (threadIdx.x >> 6);
  const float* r = src + (size_t)row * ND + lane * 8;
  float4 x0 = *(const float4*)r;
  float4 x1 = *(const float4*)(r + 4);
  float xs[8] = {x0.x, x0.y, x0.z, x0.w, x1.x, x1.y, x1.z, x1.w};
  bf16x8 hi, lo;
  float ss = 0.f;
#pragma unroll
  for (int j = 0; j < 8; ++j) {
    float x = xs[j];
    ss += x * x;
    __bf16 h = (__bf16)x;
    hi[j] = h;
    lo[j] = (__bf16)(x - (float)h);
  }
  __bf16* drow = dst + (size_t)row * 1024 + lane * 8;
  *(bf16x8*)drow = hi;
  *(bf16x8*)(drow + 512) = lo;
#pragma unroll
  for (int m = 1; m < 64; m <<= 1) ss += __shfl_xor(ss, m);
  if (lane == 0) sumsq[row] = ss;
}

// ---- 128x128 tile, 4 waves, 3 blocks/CU, SUPER-PHASE (2 K-tiles/barrier) ---
// R14 lesson: with all waits slack, the ~810 cyc/block-phase wall is FIXED
// per-phase cost (barrier + issue serialization), 48x. This halves the count:
// each barrier-phase p handles tiles u=2p, v=2p+1 (32 MFMA/phase).
// B: LDS 6 regions x 8 KB (region = tile % 6), stage distance 4 tiles.
// A: 2 reg buffers; prefetch A(2p+2)->aE AFTER MFMA1(aE) and A(2p+3)->aO
// AFTER MFMA2(aO) (in-order issue: MFMA consumed operands before the
// overwriting load issues -> 2 buffers suffice).
// Per-phase issue order: D x4 (stage 2p+4,2p+5) | b0,b1 ds_reads |
//   W1 = vmcnt(8) lgkmcnt(4) | MFMA1 x16 (aE, b0) | PE x4 (A(2p+2)->aE) |
//   W2 = vmcnt(8) lgkmcnt(0) | MFMA2 x16 (aO, b1) | PO x4 (A(2p+3)->aO) |
//   s_barrier.
// Wait math (newest-first at W1: p.D4, p-1.PO4 -> vmcnt(8) forces p-1.PE
// (=A(2p), consumed by MFMA1) and p-1.D (stages of 2p+2,2p+3: published by
// this barrier, read at p+1)). At W2 (newest: p.PE4, p.D4): forces p-1.PO
// (=A(2p+1)). Stage RAW: tile staged at p, forced at p+1.W1, published at
// p+1 barrier, read at p+2. Region WAR: region (2p+4)%6 last read at p-1
// (b-reads complete by p-1's lgkm waits, before p-1's barrier); overwrite
// issues after that barrier. Wrap tiles 48-51: dead re-stage/load, in-bounds.
// REGISTER BUDGET: acc(64 AGPR) + A(32) + b0/b1(32) + addr ~145 <= 170 from
// (256,3); 3 blocks/CU; LDS 48 KB x3 = 144 <= 160. Watch WRITE_SIZE (spill).
// B slot swizzle (R6-verified, 0 conflicts): 16B-slot
//   q(row,c16) = (row>>1)*8 + (row&1)*4 + ((c16 + (row>>1)) & 3)

__device__ __attribute__((always_inline)) static inline
void gll16(const char* src, char* dst) {
  __builtin_amdgcn_global_load_lds(
      (const __attribute__((address_space(1))) void*)src,
      (__attribute__((address_space(3))) void*)dst, 16, 0, 0);
}

__device__ __attribute__((always_inline)) static inline
bf16x8 lds_read(unsigned addr) {
  i32x4 d;
  asm volatile("ds_read_b128 %0, %1" : "=v"(d) : "v"(addr));
  return __builtin_bit_cast(bf16x8, d);
}

#define FENCE asm volatile("" ::: "memory")

__device__ __attribute__((always_inline)) static inline
int bByte(int t) {                    // B phys byte for logical tile t (wraps)
  int tt = (t < NTILE) ? t : t - NTILE;
  return (tt & 15) * 64 + (tt >= 32 ? 1024 : 0);
}

template <int J>   // J = p % 3; read regions 2J, 2J+1; stage (2J+4)%6,(2J+5)%6
__device__ __attribute__((always_inline)) static inline
void phase_op(f32x4 (&acc)[4][4], bf16x8 (&aE)[4], bf16x8 (&aO)[4],
              const char* Ab, const int (&voffA)[4],
              const char* srcBt, char* stB, unsigned bRead, int p) {
  constexpr int R0 = 2 * J, R1 = 2 * J + 1;
  constexpr int S0 = (2 * J + 4) % 6, S1 = (2 * J + 5) % 6;
  const int kB0 = bByte(2 * p + 4), kB1 = bByte(2 * p + 5);
  const int kAE = ((2 * p + 2) & 31) * 65536;
  const int kAO = ((2 * p + 3) & 31) * 65536;
  // D: stage tiles 2p+4, 2p+5
  gll16(srcBt + kB0, stB + S0 * 8192);
  gll16(srcBt + kB0 + 131072, stB + S0 * 8192 + 4096);
  gll16(srcBt + kB1, stB + S1 * 8192);
  gll16(srcBt + kB1 + 131072, stB + S1 * 8192 + 4096);
  // b reads for both sub-tiles (b0 older than b1 in lgkm order)
  bf16x8 b0[4], b1[4];
#pragma unroll
  for (int n = 0; n < 4; ++n) b0[n] = lds_read(bRead + R0 * 8192 + n * 1024);
#pragma unroll
  for (int n = 0; n < 4; ++n) b1[n] = lds_read(bRead + R1 * 8192 + n * 1024);
  asm volatile("s_waitcnt vmcnt(8) lgkmcnt(4)" ::: "memory");
  __builtin_amdgcn_sched_barrier(0);
  __builtin_amdgcn_s_setprio(1);
#pragma unroll
  for (int m = 0; m < 4; ++m)
#pragma unroll
    for (int n = 0; n < 4; ++n)
      acc[m][n] = __builtin_amdgcn_mfma_f32_16x16x32_bf16(aE[m], b0[n], acc[m][n], 0, 0, 0);
  __builtin_amdgcn_s_setprio(0);
  // PE: prefetch A(2p+2) -> aE (safe: MFMA1 consumed aE at issue)
#pragma unroll
  for (int m = 0; m < 4; ++m)
    aE[m] = *(const bf16x8*)(Ab + voffA[m] + kAE);
  asm volatile("s_waitcnt vmcnt(8) lgkmcnt(0)" ::: "memory");
  __builtin_amdgcn_sched_barrier(0);
  __builtin_amdgcn_s_setprio(1);
#pragma unroll
  for (int m = 0; m < 4; ++m)
#pragma unroll
    for (int n = 0; n < 4; ++n)
      acc[m][n] = __builtin_amdgcn_mfma_f32_16x16x32_bf16(aO[m], b1[n], acc[m][n], 0, 0, 0);
  __builtin_amdgcn_s_setprio(0);
  // PO: prefetch A(2p+3) -> aO
#pragma unroll
  for (int m = 0; m < 4; ++m)
    aO[m] = *(const bf16x8*)(Ab + voffA[m] + kAO);
  FENCE;
  __builtin_amdgcn_s_barrier();
  FENCE;
}

__global__ __launch_bounds__(256, 3) void gemm_argmin_k(const __bf16* __restrict__ A,
                                                        const __bf16* __restrict__ B,
                                                        const float* __restrict__ b2,
                                                        unsigned long long* __restrict__ best) {
  __shared__ __align__(16) char lds[49152];
  const int tid = threadIdx.x;
  const int lane = tid & 63;
  const int wid = tid >> 6;   // 0..3
  const int wm = wid >> 1;    // 2 wave-rows (64 rows each)
  const int wn = wid & 1;     // 2 wave-cols (64 cols each)

  // XCD-chunk swizzle (3088 % 8 == 0 -> bijective): 8 M-blocks of a B-panel
  // land on one XCD -> panel fetched into L2 once (R6: FETCH 606->64 MB).
  const int d = blockIdx.x;
  const int o = (d & 7) * 386 + (d >> 3);
  const int bm = (o & 7) * 128;
  const int bn = (o >> 3) * 128;

  const int r = lane & 15, g = lane >> 4;
  const int rh = r >> 1;
  const unsigned lds0 =
      (unsigned)(uintptr_t)(const __attribute__((address_space(3))) char*)(const char*)lds;
  const unsigned bRead = lds0 + wn * 4096 + rh * 128 + (r & 1) * 64 + (((g + rh) & 3) << 4);

  // A per-lane byte offsets, fragment-ordered layout:
  const char* Ab = (const char*)A;
  int voffA[4];
#pragma unroll
  for (int m = 0; m < 4; ++m)
    voffA[m] = ((bm >> 4) + wm * 4 + m) * 1024 + lane * 16;

  // B stage-side lane mapping (inverse of the slot swizzle); 256 threads
  // cover 512 slots of the 8 KB region (rows 0-63 and +64 via 2nd gll16)
  const int srow = 2 * (tid >> 3) + ((tid >> 2) & 1);
  const int sc16 = ((tid & 3) - (tid >> 3)) & 3;
  const char* srcBt = (const char*)B + (size_t)(bn + srow) * 2048 + sc16 * 16;
  char* stB = (char*)lds + tid * 16;

  f32x4 acc[4][4] = {};
  bf16x8 aE[4], aO[4];

  // prologue: stage tiles 0..3 -> regions 0..3; A(0)->aE, A(1)->aO.
  // vmcnt(12) forces tiles 0,1 (read at phase 0); tiles 2,3 forced at
  // phase-0 W1/W2 (published by phase-0 barrier, read at phase 1).
  gll16(srcBt + bByte(0), stB + 0);
  gll16(srcBt + bByte(0) + 131072, stB + 4096);
  gll16(srcBt + bByte(1), stB + 8192);
  gll16(srcBt + bByte(1) + 131072, stB + 8192 + 4096);
  gll16(srcBt + bByte(2), stB + 16384);
  gll16(srcBt + bByte(2) + 131072, stB + 16384 + 4096);
  gll16(srcBt + bByte(3), stB + 24576);
  gll16(srcBt + bByte(3) + 131072, stB + 24576 + 4096);
#pragma unroll
  for (int m = 0; m < 4; ++m)
    aE[m] = *(const bf16x8*)(Ab + voffA[m]);
#pragma unroll
  for (int m = 0; m < 4; ++m)
    aO[m] = *(const bf16x8*)(Ab + voffA[m] + 65536);
  asm volatile("s_waitcnt vmcnt(12)" ::: "memory");
  FENCE;
  __builtin_amdgcn_s_barrier();
  FENCE;

#pragma unroll 1
  for (int it = 0; it < 8; ++it) {
    const int p0 = 3 * it;
    phase_op<0>(acc, aE, aO, Ab, voffA, srcBt, stB, bRead, p0 + 0);
    phase_op<1>(acc, aE, aO, Ab, voffA, srcBt, stB, bRead, p0 + 1);
    phase_op<2>(acc, aE, aO, Ab, voffA, srcBt, stB, bRead, p0 + 2);
  }

  // epilogue: fused argmin. C/D map: col = lane&15, row = (lane>>4)*4 + reg.
  float bb[4];
#pragma unroll
  for (int n = 0; n < 4; ++n) bb[n] = b2[bn + wn * 64 + n * 16 + r];
#pragma unroll
  for (int m = 0; m < 4; ++m) {
#pragma unroll
    for (int reg = 0; reg < 4; ++reg) {
      unsigned long long pk = ~0ull;
#pragma unroll
      for (int n = 0; n < 4; ++n) {
        float s = bb[n] - 2.0f * acc[m][n][reg];
        unsigned long long cand = pack_sv(s, (unsigned)(bn + wn * 64 + n * 16 + r));
        pk = (cand < pk) ? cand : pk;
      }
#pragma unroll
      for (int msk = 1; msk < 16; msk <<= 1) {
        unsigned long long o2 = __shfl_xor(pk, msk);
        pk = (o2 < pk) ? o2 : pk;
      }
      if (r == 0) atomicMin(&best[bm + wm * 64 + m * 16 + g * 4 + reg], pk);
    }
  }
}

// Fallback (small ws): exact fp32 squared distance, fused argmin.
__global__ __launch_bounds__(256) void naive_argmin_k(const float* __restrict__ A,
                                                      const float* __restrict__ B,
                                                      unsigned long long* __restrict__ best) {
  __shared__ float arow[ND];
  int p = blockIdx.y;
  unsigned v = blockIdx.x * 256 + threadIdx.x;
  for (int i = threadIdx.x; i < ND; i += 256) arow[i] = A[(size_t)p * ND + i];
  __syncthreads();
  const float4* br = (const float4*)(B + (size_t)v * ND);
  float s = 0.f;
#pragma unroll 4
  for (int i = 0; i < ND / 4; ++i) {
    float4 b = br[i];
    const float4 a = *(const float4*)&arow[i * 4];
    float d0 = a.x - b.x, d1 = a.y - b.y, d2 = a.z - b.z, d3 = a.w - b.w;
    s += d0 * d0 + d1 * d1 + d2 * d2 + d3 * d3;
  }
  unsigned long long pk = pack_sv(s, v);
#pragma unroll
  for (int msk = 1; msk < 64; msk <<= 1) {
    unsigned long long o = __shfl_xor(pk, msk);
    pk = (o < pk) ? o : pk;
  }
  if ((threadIdx.x & 63) == 0) atomicMin(&best[p], pk);
}

// Gather winning rows + ids (ids written as float, d_out is read as flat f32).
__global__ __launch_bounds__(128) void gather_k(const unsigned long long* __restrict__ best,
                                                const float* __restrict__ clip,
                                                float* __restrict__ out) {
  int p = blockIdx.x;
  unsigned long long pk = best[p];
  unsigned v = (unsigned)(pk & 0xffffffffull);
  const float4* src = (const float4*)(clip + (size_t)v * ND);
  float4* dst = (float4*)(out + (size_t)p * ND);
  dst[threadIdx.x] = src[threadIdx.x];
  if (threadIdx.x == 0) out[(size_t)NP * ND + p] = (float)v;
}

extern "C" void kernel_launch(void* const* d_in, const int* in_sizes, int n_in,
                              void* d_out, int out_size, void* d_ws, size_t ws_size,
                              hipStream_t stream) {
  const float* prompt = (const float*)d_in[0];
  const float* clip = (const float*)d_in[1];
  float* out = (float*)d_out;

  // workspace layout
  size_t off = 0;
  unsigned long long* best = (unsigned long long*)d_ws;
  off += (size_t)NP * 8;
  float* b2 = (float*)((char*)d_ws + off);
  off += (size_t)NV * 4;
  off = (off + 255) & ~(size_t)255;
  __bf16* Ap = (__bf16*)((char*)d_ws + off);
  off += (size_t)NP * 1024 * 2;                // 2 MiB  fragment-ordered
  __bf16* Bp = (__bf16*)((char*)d_ws + off);
  off += (size_t)NV * 1024 * 2;                // 96.5 MiB [hi|lo]
  const size_t need = off;

  if (ws_size >= need) {
    hipMemsetAsync(best, 0xFF, (size_t)NP * 8, stream);
    pack_a_k<<<NP / 4, 256, 0, stream>>>(prompt, Ap);
    pack_b_k<<<NV / 4, 256, 0, stream>>>(clip, Bp, b2);
    gemm_argmin_k<<<dim3(8 * 386), 256, 0, stream>>>(Ap, Bp, b2, best);
    gather_k<<<NP, 128, 0, stream>>>(best, clip, out);
  } else {
    // fallback: exact fp32, needs only the 8 KiB `best` array
    hipMemsetAsync(best, 0xFF, (size_t)NP * 8, stream);
    dim3 grid(NV / 256, NP);
    naive_argmin_k<<<grid, 256, 0, stream>>>(prompt, clip, best);
    gather_k<<<NP, 128, 0, stream>>>(best, clip, out);
  }
}